// Round 1
// 3173.123 us; speedup vs baseline: 1.3707x; 1.3707x over previous
//
#include <hip/hip_runtime.h>
#include <hip/hip_bf16.h>
#include <cstdint>
#include <cstddef>

#define BB 16
#define TT 256
#define EE 256
#define HH 512
#define VV 32000
#define G4 2048   // 4*H

typedef __attribute__((ext_vector_type(8))) short short8;   // 8 bf16 (4 VGPRs)
typedef __attribute__((ext_vector_type(4))) float f32x4;    // 4 f32 acc

// f32 -> bf16 with round-to-nearest-even (manual, avoids API differences)
__device__ __forceinline__ short f2bf(float x){
    union { float f; unsigned u; } v; v.f = x;
    unsigned r = v.u + 0x7fffu + ((v.u >> 16) & 1u);
    return (short)(r >> 16);
}

__device__ __forceinline__ float sigf(float x){ return 1.0f / (1.0f + __expf(-x)); }
__device__ __forceinline__ float tanh_(float x){ return 2.0f / (1.0f + __expf(-2.0f * x)) - 1.0f; }

// ---------------- K0a: embedding gather + cvt to bf16 -----------------------
__global__ void k_gather(const int* __restrict__ tok, const float* __restrict__ emb,
                         short* __restrict__ xbf){
    int m = blockIdx.x;
    int t = tok[m];
    int k = threadIdx.x;               // 256 threads == EE
    xbf[(size_t)m * EE + k] = f2bf(emb[(size_t)t * EE + k]);
}

// ---------------- K0b: transpose + cvt: in f32 [K][N] -> out bf16 [N][K] ----
__global__ void k_transpose(const float* __restrict__ in, short* __restrict__ out,
                            int K, int N){
    __shared__ short tile[64][65];
    int kb = blockIdx.x * 64, nb = blockIdx.y * 64;
    int c = threadIdx.x & 63, r0 = threadIdx.x >> 6;
    for (int r = r0; r < 64; r += 4)
        tile[r][c] = f2bf(in[(size_t)(kb + r) * N + nb + c]);
    __syncthreads();
    for (int r = r0; r < 64; r += 4)
        out[(size_t)(nb + r) * K + kb + c] = tile[c][r];
}

// ---------------- K1: xW1 = x @ W1 + b1  (bf16 MFMA, f32 out) ---------------
__global__ __launch_bounds__(256) void k_xw1(const short* __restrict__ A,
                                             const short* __restrict__ Bsw,
                                             const float* __restrict__ bias,
                                             float* __restrict__ out){
    int g = blockIdx.x;
    int mb = g & 15, nb = g >> 4;                    // 16 x 64 blocks
    int wave = threadIdx.x >> 6, lane = threadIdx.x & 63;
    int ln = lane & 15, q = lane >> 4;
    int col0 = nb * 32 + ln;
    short8 bf[2][8];
    for (int nt = 0; nt < 2; nt++){
        const short* bp = Bsw + (size_t)(col0 + nt * 16) * EE + q * 8;
        for (int ks = 0; ks < 8; ks++) bf[nt][ks] = *(const short8*)(bp + ks * 32);
    }
    float bi0 = bias[col0], bi1 = bias[col0 + 16];
    int mrow0 = mb * 256 + wave * 64;
    for (int mt = 0; mt < 4; mt++){
        f32x4 a0 = {bi0, bi0, bi0, bi0}, a1 = {bi1, bi1, bi1, bi1};
        const short* ap = A + (size_t)(mrow0 + mt * 16 + ln) * EE + q * 8;
        for (int ks = 0; ks < 8; ks++){
            short8 af = *(const short8*)(ap + ks * 32);
            a0 = __builtin_amdgcn_mfma_f32_16x16x32_bf16(af, bf[0][ks], a0, 0, 0, 0);
            a1 = __builtin_amdgcn_mfma_f32_16x16x32_bf16(af, bf[1][ks], a1, 0, 0, 0);
        }
        for (int r = 0; r < 4; r++){
            int row = mrow0 + mt * 16 + q * 4 + r;
            out[(size_t)row * G4 + nb * 32 + ln]      = a0[r];
            out[(size_t)row * G4 + nb * 32 + 16 + ln] = a1[r];
        }
    }
}

// ---------------- K2: fused 2-layer LSTM recurrence (persistent) ------------
// 64 WGs x 256 thr. WGs [0,32): layer1, [32,64): layer2 (one step behind).
// Sync redesign vs previous version:
//   - two independent 32-WG barriers (layer1 never waits on layer2)
//   - bar[0]=L1 count, bar[1]=L1 phase (doubles as progress for L2 consumers)
//   - bar[2]=L2 count, bar[3]=L2 phase
//   - spin with RELAXED agent atomic loads (coherent sc1 load, NO buffer_inv
//     per iteration); exactly ONE acquire fence per step after poll succeeds.
//   - arrivals: RELEASE fetch_add (waitcnt+wbl2 once), master stores phase
//     with RELEASE.
__global__ __launch_bounds__(256) void k_lstm(
        const float* __restrict__ xW1,   // [b*T+t][2048] f32 (includes b1)
        const float* __restrict__ U1,    // [512][2048] f32
        const float* __restrict__ W2,    // [512][2048] f32
        const float* __restrict__ U2,    // [512][2048] f32
        const float* __restrict__ b2,    // [2048] f32
        short* __restrict__ hs1,         // [T][B][H] bf16
        short* __restrict__ hs2,         // [T][B][H] bf16
        unsigned* bar){
    __shared__ float zl[4][16][16];
    int wg = blockIdx.x;
    int layer = wg >> 5;
    int w = wg & 31;
    int wave = threadIdx.x >> 6, lane = threadIdx.x & 63;
    int ln = lane & 15, q = lane >> 4;
    int col = wave * HH + w * 16 + ln;   // z-column in [0,2048)
    int bc = threadIdx.x >> 4, hc = threadIdx.x & 15;  // gate-update ownership
    float creg = 0.f;

    if (layer == 0){
        short8 fU1[16];
        for (int ks = 0; ks < 16; ks++){
            short8 v;
            for (int j = 0; j < 8; j++)
                v[j] = f2bf(U1[(size_t)(ks * 32 + q * 8 + j) * G4 + col]);
            fU1[ks] = v;
        }
        for (int s = 0; s < TT; s++){
            f32x4 acc;
            for (int r = 0; r < 4; r++)                    // C-init = xW1[b][s][col]
                acc[r] = xW1[((size_t)(q * 4 + r) * TT + s) * G4 + col];
            if (s > 0){
                const short* ap = hs1 + (size_t)(s - 1) * BB * HH + ln * HH + q * 8;
                for (int ks = 0; ks < 16; ks++){
                    short8 af = *(const short8*)(ap + ks * 32);
                    acc = __builtin_amdgcn_mfma_f32_16x16x32_bf16(af, fU1[ks], acc, 0, 0, 0);
                }
            }
            for (int r = 0; r < 4; r++) zl[wave][q * 4 + r][ln] = acc[r];
            __syncthreads();                               // S1: zl ready
            {
                float zi = zl[0][bc][hc], zf = zl[1][bc][hc];
                float zg = zl[2][bc][hc], zo = zl[3][bc][hc];
                float ig = sigf(zi), fg = sigf(zf), gg = tanh_(zg), og = sigf(zo);
                creg = fg * creg + ig * gg;
                float h = og * tanh_(creg);
                hs1[(size_t)s * BB * HH + bc * HH + w * 16 + hc] = f2bf(h);
            }
            __syncthreads();                               // S2: all hs1 stores issued
            if (threadIdx.x == 0){
                unsigned old = __hip_atomic_fetch_add(&bar[0], 1u, __ATOMIC_RELEASE,
                                                      __HIP_MEMORY_SCOPE_AGENT);
                if (old == 31u){
                    __hip_atomic_store(&bar[0], 0u, __ATOMIC_RELAXED, __HIP_MEMORY_SCOPE_AGENT);
                    __hip_atomic_store(&bar[1], (unsigned)(s + 1), __ATOMIC_RELEASE,
                                       __HIP_MEMORY_SCOPE_AGENT);
                }
                if (s + 1 < TT){
                    while (__hip_atomic_load(&bar[1], __ATOMIC_RELAXED,
                                             __HIP_MEMORY_SCOPE_AGENT) < (unsigned)(s + 1)){
                        __builtin_amdgcn_s_sleep(1);
                    }
                    __builtin_amdgcn_fence(__ATOMIC_ACQUIRE, "agent");
                }
            }
            __syncthreads();                               // S3: safe to read hs1[s]
        }
    } else {
        short8 fW2[16], fU2[16];
        for (int ks = 0; ks < 16; ks++){
            short8 v, u;
            for (int j = 0; j < 8; j++){
                v[j] = f2bf(W2[(size_t)(ks * 32 + q * 8 + j) * G4 + col]);
                u[j] = f2bf(U2[(size_t)(ks * 32 + q * 8 + j) * G4 + col]);
            }
            fW2[ks] = v; fU2[ks] = u;
        }
        float b2c = b2[col];
        for (int t = 0; t < TT; t++){
            if (threadIdx.x == 0){
                // need hs1[t] (layer1 progress > t) and hs2[t-1] (own group)
                while (__hip_atomic_load(&bar[1], __ATOMIC_RELAXED,
                                         __HIP_MEMORY_SCOPE_AGENT) < (unsigned)(t + 1)){
                    __builtin_amdgcn_s_sleep(1);
                }
                if (t > 0){
                    while (__hip_atomic_load(&bar[3], __ATOMIC_RELAXED,
                                             __HIP_MEMORY_SCOPE_AGENT) < (unsigned)t){
                        __builtin_amdgcn_s_sleep(1);
                    }
                }
                __builtin_amdgcn_fence(__ATOMIC_ACQUIRE, "agent");
            }
            __syncthreads();                               // S0: inputs visible, zl free
            f32x4 acc = {b2c, b2c, b2c, b2c};
            const short* ap1 = hs1 + (size_t)t * BB * HH + ln * HH + q * 8;
            for (int ks = 0; ks < 16; ks++){
                short8 af = *(const short8*)(ap1 + ks * 32);
                acc = __builtin_amdgcn_mfma_f32_16x16x32_bf16(af, fW2[ks], acc, 0, 0, 0);
            }
            if (t > 0){
                const short* ap2 = hs2 + (size_t)(t - 1) * BB * HH + ln * HH + q * 8;
                for (int ks = 0; ks < 16; ks++){
                    short8 af = *(const short8*)(ap2 + ks * 32);
                    acc = __builtin_amdgcn_mfma_f32_16x16x32_bf16(af, fU2[ks], acc, 0, 0, 0);
                }
            }
            for (int r = 0; r < 4; r++) zl[wave][q * 4 + r][ln] = acc[r];
            __syncthreads();                               // S1: zl ready
            {
                float zi = zl[0][bc][hc], zf = zl[1][bc][hc];
                float zg = zl[2][bc][hc], zo = zl[3][bc][hc];
                float ig = sigf(zi), fg = sigf(zf), gg = tanh_(zg), og = sigf(zo);
                creg = fg * creg + ig * gg;
                float h = og * tanh_(creg);
                hs2[(size_t)t * BB * HH + bc * HH + w * 16 + hc] = f2bf(h);
            }
            __syncthreads();                               // S2: all hs2 stores issued
            if (threadIdx.x == 0){
                unsigned old = __hip_atomic_fetch_add(&bar[2], 1u, __ATOMIC_RELEASE,
                                                      __HIP_MEMORY_SCOPE_AGENT);
                if (old == 31u){
                    __hip_atomic_store(&bar[2], 0u, __ATOMIC_RELAXED, __HIP_MEMORY_SCOPE_AGENT);
                    __hip_atomic_store(&bar[3], (unsigned)(t + 1), __ATOMIC_RELEASE,
                                       __HIP_MEMORY_SCOPE_AGENT);
                }
            }
            // next iteration's S0 poll provides the wait; no extra barrier here
        }
    }
}

// ---------------- K3: logits = hs2 @ Wd + bd (bf16 MFMA, f32 out) -----------
// B-stationary rewrite: 1000 blocks, each owns 32 vocab cols, loads B-frags
// ONCE into regs (launch_bounds(256,2) -> 256 VGPR budget so they stay
// resident), loops over all 4096 rows. B traffic 512MB -> 32MB.
__global__ __launch_bounds__(256, 2) void k_dense(const short* __restrict__ A,
                                                  const short* __restrict__ Bsw,
                                                  const float* __restrict__ bias,
                                                  float* __restrict__ out){
    int nb = blockIdx.x;                 // [0,1000)
    int wave = threadIdx.x >> 6, lane = threadIdx.x & 63;
    int ln = lane & 15, q = lane >> 4;
    int col0 = nb * 32 + ln;
    short8 bf[2][16];
    for (int nt = 0; nt < 2; nt++){
        const short* bp = Bsw + (size_t)(col0 + nt * 16) * HH + q * 8;
        for (int ks = 0; ks < 16; ks++) bf[nt][ks] = *(const short8*)(bp + ks * 32);
    }
    float bi0 = bias[col0], bi1 = bias[col0 + 16];
    for (int mb = 0; mb < 16; mb++){
        int mrow0 = mb * 256 + wave * 64;
        for (int mt = 0; mt < 4; mt++){
            int m = mrow0 + mt * 16 + ln;
            int arow = (m & 255) * BB + (m >> 8);    // t*16 + b
            const short* ap = A + (size_t)arow * HH + q * 8;
            f32x4 a0 = {bi0, bi0, bi0, bi0}, a1 = {bi1, bi1, bi1, bi1};
            for (int ks = 0; ks < 16; ks++){
                short8 af = *(const short8*)(ap + ks * 32);
                a0 = __builtin_amdgcn_mfma_f32_16x16x32_bf16(af, bf[0][ks], a0, 0, 0, 0);
                a1 = __builtin_amdgcn_mfma_f32_16x16x32_bf16(af, bf[1][ks], a1, 0, 0, 0);
            }
            int rowb = mrow0 + mt * 16 + q * 4;
            for (int r = 0; r < 4; r++){
                out[(size_t)(rowb + r) * VV + nb * 32 + ln]      = a0[r];
                out[(size_t)(rowb + r) * VV + nb * 32 + 16 + ln] = a1[r];
            }
        }
    }
}

extern "C" void kernel_launch(void* const* d_in, const int* in_sizes, int n_in,
                              void* d_out, int out_size, void* d_ws, size_t ws_size,
                              hipStream_t stream){
    const int*   tokens = (const int*)  d_in[0];
    const float* emb    = (const float*)d_in[1];
    const float* W1     = (const float*)d_in[2];
    const float* U1     = (const float*)d_in[3];
    const float* b1     = (const float*)d_in[4];
    const float* W2     = (const float*)d_in[5];
    const float* U2     = (const float*)d_in[6];
    const float* b2     = (const float*)d_in[7];
    const float* Wd     = (const float*)d_in[8];
    const float* bd     = (const float*)d_in[9];
    float* out = (float*)d_out;

    char* ws = (char*)d_ws;
    size_t off = 0;
    auto alloc = [&](size_t bytes){
        void* p = ws + off; off += (bytes + 255) & ~(size_t)255; return p;
    };
    float*    xW1  = (float*)   alloc((size_t)4096 * 2048 * 4);   // 32 MB
    short*    hs1  = (short*)   alloc((size_t)256 * 16 * 512 * 2);//  4 MB
    short*    hs2  = (short*)   alloc((size_t)256 * 16 * 512 * 2);//  4 MB
    short*    xbf  = (short*)   alloc((size_t)4096 * 256 * 2);    //  2 MB
    short*    W1sw = (short*)   alloc((size_t)2048 * 256 * 2);    //  1 MB
    short*    Wdsw = (short*)   alloc((size_t)32000 * 512 * 2);   // 32 MB
    unsigned* bar  = (unsigned*)alloc(256);

    hipMemsetAsync(bar, 0, 16, stream);
    k_gather<<<4096, 256, 0, stream>>>(tokens, emb, xbf);
    k_transpose<<<dim3(4, 32), 256, 0, stream>>>(W1, W1sw, 256, 2048);
    k_transpose<<<dim3(8, 500), 256, 0, stream>>>(Wd, Wdsw, 512, 32000);
    k_xw1<<<1024, 256, 0, stream>>>(xbf, W1sw, b1, xW1);
    k_lstm<<<64, 256, 0, stream>>>(xW1, U1, W2, U2, b2, hs1, hs2, bar);
    k_dense<<<1000, 256, 0, stream>>>(hs2, Wdsw, bd, out);
}